// Round 9
// baseline (125.210 us; speedup 1.0000x reference)
//
#include <hip/hip_runtime.h>
#include <math.h>

#define TT 1024   // tokens
#define HH 1024   // hidden
#define MM 512    // moe intermediate
#define NE 16     // routed experts (blockIdx.z == NE -> shared expert)
// TOP_K = 2, SCALE = 2.5, NORM_TOPK = true

typedef _Float16 f16;
typedef _Float16 f16x8 __attribute__((ext_vector_type(8)));
typedef float f32x4 __attribute__((ext_vector_type(4)));

// LDS rows padded to 68 f16 (136 B): bank = (2*row + col/2) % 32.
// All staging writes (b128) and fragment reads (b128) land 8 bank-touches/bank
// = the wave64 b128 structural minimum (verified: SQ_LDS_BANK_CONFLICT = 0).
#define LPAD 68

// Phase barrier, m201-style: NO "memory" clobber (a may-store asm forces the
// backend to drain vmcnt(0), re-exposing full HBM latency every phase — the
// r6==r7 null result). Ordering is pinned by sched_barrier(0) instead.
// lgkmcnt(0) makes ds_writes visible; global prefetch loads STAY IN FLIGHT.
#define BAR() { __builtin_amdgcn_sched_barrier(0);              \
                asm volatile("s_waitcnt lgkmcnt(0)");           \
                __builtin_amdgcn_s_barrier();                   \
                __builtin_amdgcn_sched_barrier(0); }

// ---------------- router ----------------
__global__ __launch_bounds__(256) void router_k(
    const float* __restrict__ x, const float* __restrict__ gate_w,
    int* __restrict__ counts, int* __restrict__ token_list, float* __restrict__ weight_list)
{
    const int wave = threadIdx.x >> 6;
    const int lane = threadIdx.x & 63;
    const int t = (blockIdx.x << 2) + wave;
    const float* xr = x + (size_t)t * HH;
    float xv[16];
#pragma unroll
    for (int i = 0; i < 16; ++i) xv[i] = xr[lane + (i << 6)];
    float sc[NE];
#pragma unroll
    for (int e = 0; e < NE; ++e) {
        const float* gr = gate_w + e * HH;
        float acc = 0.f;
#pragma unroll
        for (int i = 0; i < 16; ++i) acc = fmaf(xv[i], gr[lane + (i << 6)], acc);
#pragma unroll
        for (int off = 32; off > 0; off >>= 1) acc += __shfl_down(acc, off, 64);
        sc[e] = acc;   // valid on lane 0
    }
    if (lane == 0) {
        float l1 = -1e30f, l2 = -1e30f; int i1 = 0, i2 = 0;
#pragma unroll
        for (int e = 0; e < NE; ++e) {
            float v = sc[e];
            if (v > l1) { l2 = l1; i2 = i1; l1 = v; i1 = e; }
            else if (v > l2) { l2 = v; i2 = e; }
        }
        float w1 = 1.f / (1.f + __expf(-l1));
        float w2 = 1.f / (1.f + __expf(-l2));
        const float inv = 2.5f / (w1 + w2 + 1e-20f);
        w1 *= inv; w2 *= inv;
        int s1 = atomicAdd(&counts[i1], 1);
        token_list[i1 * TT + s1] = t;
        weight_list[i1 * TT + s1] = w1;
        int s2 = atomicAdd(&counts[i2], 1);
        token_list[i2 * TT + s2] = t;
        weight_list[i2 * TT + s2] = w2;
    }
}

__global__ void prefix_k(const int* __restrict__ counts, int* __restrict__ offs)
{
    if (threadIdx.x == 0 && blockIdx.x == 0) {
        int acc = 0;
#pragma unroll
        for (int e = 0; e < NE; ++e) { offs[e] = acc; acc += counts[e]; }
        offs[NE] = acc;
    }
}

// ================= fused gate/up =================
// grid = (MM/32 n-tiles, TT/64 row-tiles, NE+1). BM=64, BN=32, BK=64.
// 256 thr (4 waves, 2m x 2n of 16). Depth-3 register pipeline (tile t loaded in
// phase t-3), dbuf LDS, 1 lgkm-only barrier/phase. Outstanding VMEM = 3 sets x
// 20 instr = 60 <= 63 vmcnt => all register-dependency waits are counted.

#define GU_NT 16

#define GU_LOAD(PA, PB, K0)                                               \
  { _Pragma("unroll") for (int u = 0; u < 4; ++u) {                       \
      float4 v = *(const float4*)(arow + (K0) + skb + (u << 2));          \
      PA[4*u] = v.x; PA[4*u+1] = v.y; PA[4*u+2] = v.z; PA[4*u+3] = v.w; } \
    _Pragma("unroll") for (int i = 0; i < 16; ++i)                        \
      PB[i] = bsrc[(size_t)((K0) + bkb + i) * MM]; }

#define GU_CW(PA, PB, AS, BGS, BUS)                                       \
  { f16x8 a0, a1, b0, b1;                                                 \
    _Pragma("unroll") for (int j = 0; j < 8; ++j) {                       \
      a0[j] = (f16)PA[j]; a1[j] = (f16)PA[8+j];                           \
      b0[j] = (f16)PB[j]; b1[j] = (f16)PB[8+j]; }                         \
    *(f16x8*)&AS[sr][skb] = a0; *(f16x8*)&AS[sr][skb+8] = a1;             \
    f16 (*bd)[LPAD] = bmx ? BUS : BGS;                                    \
    *(f16x8*)&bd[bn][bkb] = b0; *(f16x8*)&bd[bn][bkb+8] = b1; }

#define GU_COMP(AS, BGS, BUS)                                             \
  { _Pragma("unroll") for (int h = 0; h < 2; ++h) {                       \
      const int kf = (h << 5) + (lg << 3);                                \
      f16x8 af[2], bgv, buv;                                              \
      af[0] = *(const f16x8*)&AS[wm + lm][kf];                            \
      af[1] = *(const f16x8*)&AS[wm + 16 + lm][kf];                       \
      bgv = *(const f16x8*)&BGS[wn + lm][kf];                             \
      buv = *(const f16x8*)&BUS[wn + lm][kf];                             \
      _Pragma("unroll") for (int fi = 0; fi < 2; ++fi) {                  \
        accg[fi] = __builtin_amdgcn_mfma_f32_16x16x32_f16(af[fi], bgv, accg[fi], 0, 0, 0); \
        accu[fi] = __builtin_amdgcn_mfma_f32_16x16x32_f16(af[fi], buv, accu[fi], 0, 0, 0); } } }

// phase T: load tile T+3 into set SL=(T%3); stage tile T+1 (set SC=(T+1)%3)
// into LDS LW=(T+1)%2; compute tile T from LDS LC=T%2.  All indices literal.
#define GU_PH(T, SL, SC, LW, LC)                                          \
  { if ((T) + 3 < GU_NT) GU_LOAD(pa##SL, pb##SL, ((T)+3) << 6)            \
    if ((T) + 1 < GU_NT) GU_CW(pa##SC, pb##SC, As##LW, Bgs##LW, Bus##LW)  \
    GU_COMP(As##LC, Bgs##LC, Bus##LC)                                     \
    BAR() }

__global__ __launch_bounds__(256) void gu_k(
    const float* __restrict__ x,
    const float* __restrict__ w_gate, const float* __restrict__ w_up,
    const float* __restrict__ ws_gate, const float* __restrict__ ws_up,
    const int* __restrict__ counts, const int* __restrict__ offs,
    const int* __restrict__ token_list, f16* __restrict__ rinter)
{
    const int e = blockIdx.z;
    int cnt, slot0;
    const float *wgp, *wup;
    if (e < NE) {
        cnt = counts[e]; slot0 = offs[e];
        wgp = w_gate + (size_t)e * HH * MM;
        wup = w_up   + (size_t)e * HH * MM;
    } else {
        cnt = TT; slot0 = 2 * TT;
        wgp = ws_gate; wup = ws_up;
    }
    const int r0 = blockIdx.y << 6;
    if (r0 >= cnt) return;
    const int n0 = blockIdx.x << 5;

    __shared__ f16 As0[64][LPAD], Bgs0[32][LPAD], Bus0[32][LPAD];
    __shared__ f16 As1[64][LPAD], Bgs1[32][LPAD], Bus1[32][LPAD];
    __shared__ int toks[64];

    const int tid = threadIdx.x;
    if (tid < 64) {
        int i = r0 + tid; if (i >= cnt) i = cnt - 1;
        toks[tid] = (e < NE) ? token_list[e * TT + i] : i;
    }
    __syncthreads();

    const int sr  = tid & 63;
    const int skb = (tid >> 6) << 4;
    const int bmx = tid >> 7;            // 0: gate, 1: up
    const int bi  = tid & 127;
    const int bn  = bi & 31;
    const int bkb = (bi >> 5) << 4;
    const float* bsrc = (bmx ? wup : wgp) + n0 + bn;

    const int w = tid >> 6, l = tid & 63;
    const int wm = (w >> 1) << 5;        // 0, 32
    const int wn = (w & 1) << 4;         // 0, 16
    const int lm = l & 15, lg = l >> 4;

    const float* arow = x + (size_t)toks[sr] * HH;

    f32x4 accg[2] = {}, accu[2] = {};
    float pa0[16], pb0[16], pa1[16], pb1[16], pa2[16], pb2[16];

    // prologue: tiles 0,1,2 in flight; tile0 -> LDS0 (counted wait: 40 newer remain)
    GU_LOAD(pa0, pb0, 0)
    GU_LOAD(pa1, pb1, 64)
    GU_LOAD(pa2, pb2, 128)
    GU_CW(pa0, pb0, As0, Bgs0, Bus0)
    BAR()

    GU_PH(0,0,1,1,0)  GU_PH(1,1,2,0,1)  GU_PH(2,2,0,1,0)  GU_PH(3,0,1,0,1)
    GU_PH(4,1,2,1,0)  GU_PH(5,2,0,0,1)  GU_PH(6,0,1,1,0)  GU_PH(7,1,2,0,1)
    GU_PH(8,2,0,1,0)  GU_PH(9,0,1,0,1)  GU_PH(10,1,2,1,0) GU_PH(11,2,0,0,1)
    GU_PH(12,0,1,1,0) GU_PH(13,1,2,0,1) GU_PH(14,2,0,1,0) GU_PH(15,0,0,0,1)

    // epilogue: silu(g)*u -> f16; C/D: col=lane&15, row=(lane>>4)*4+reg
#pragma unroll
    for (int fi = 0; fi < 2; ++fi)
#pragma unroll
        for (int rr = 0; rr < 4; ++rr) {
            const int m = wm + (fi << 4) + (lg << 2) + rr;
            if (r0 + m < cnt) {
                float g = accg[fi][rr], u = accu[fi][rr];
                float s = g / (1.f + __expf(-g));
                rinter[(size_t)(slot0 + r0 + m) * MM + n0 + wn + lm] = (f16)(s * u);
            }
        }
}

// ================= down: out[token] += weight * (rinter @ Wd) =================
// grid = (HH/32, TT/64, NE+1). BM=64, BN=32. 10 VMEM/set, depth-3 = 30 outstanding.

#define DN_NT 8

#define DN_LOAD(QA, QB, PB, K0)                                           \
  { QA = *(const f16x8*)(arow + (K0) + skb);                              \
    QB = *(const f16x8*)(arow + (K0) + skb + 8);                          \
    _Pragma("unroll") for (int i = 0; i < 8; ++i)                         \
      PB[i] = bsrc[(size_t)((K0) + bkb + i) * HH]; }

#define DN_CW(QA, QB, PB, AS, BS)                                         \
  { f16x8 b0;                                                             \
    _Pragma("unroll") for (int j = 0; j < 8; ++j) b0[j] = (f16)PB[j];     \
    *(f16x8*)&AS[sr][skb] = QA; *(f16x8*)&AS[sr][skb+8] = QB;             \
    *(f16x8*)&BS[bn][bkb] = b0; }

#define DN_COMP(AS, BS)                                                   \
  { _Pragma("unroll") for (int h = 0; h < 2; ++h) {                       \
      const int kf = (h << 5) + (lg << 3);                                \
      f16x8 af[2], bv;                                                    \
      af[0] = *(const f16x8*)&AS[wm + lm][kf];                            \
      af[1] = *(const f16x8*)&AS[wm + 16 + lm][kf];                       \
      bv = *(const f16x8*)&BS[wn + lm][kf];                               \
      _Pragma("unroll") for (int fi = 0; fi < 2; ++fi)                    \
        acc[fi] = __builtin_amdgcn_mfma_f32_16x16x32_f16(af[fi], bv, acc[fi], 0, 0, 0); } }

#define DN_PH(T, SL, SC, LW, LC)                                          \
  { if ((T) + 3 < DN_NT) DN_LOAD(qa##SL, qb##SL, pr##SL, ((T)+3) << 6)    \
    if ((T) + 1 < DN_NT) DN_CW(qa##SC, qb##SC, pr##SC, As##LW, Bs##LW)    \
    DN_COMP(As##LC, Bs##LC)                                               \
    BAR() }

__global__ __launch_bounds__(256) void down_k(
    const f16* __restrict__ rinter,
    const float* __restrict__ w_down, const float* __restrict__ ws_down,
    const int* __restrict__ counts, const int* __restrict__ offs,
    const int* __restrict__ token_list, const float* __restrict__ weight_list,
    float* __restrict__ out)
{
    const int e = blockIdx.z;
    int cnt, slot0; const float* wdp;
    if (e < NE) { cnt = counts[e]; slot0 = offs[e]; wdp = w_down + (size_t)e * MM * HH; }
    else        { cnt = TT; slot0 = 2 * TT; wdp = ws_down; }
    const int r0 = blockIdx.y << 6;
    if (r0 >= cnt) return;
    const int n0 = blockIdx.x << 5;   // of HH

    __shared__ f16 As0[64][LPAD], Bs0[32][LPAD];
    __shared__ f16 As1[64][LPAD], Bs1[32][LPAD];

    const int tid = threadIdx.x;
    const int sr  = tid & 63;
    const int skb = (tid >> 6) << 4;
    const int bn  = tid & 31;
    const int bkb = (tid >> 5) << 3;   // 8 k per thread, 256 threads cover 64x32
    const float* bsrc = wdp + n0 + bn;

    const int w = tid >> 6, l = tid & 63;
    const int wm = (w >> 1) << 5, wn = (w & 1) << 4;
    const int lm = l & 15, lg = l >> 4;

    int ari = r0 + sr; if (ari >= cnt) ari = cnt - 1;
    const f16* arow = rinter + (size_t)(slot0 + ari) * MM;

    f32x4 acc[2] = {};
    f16x8 qa0, qb0, qa1, qb1, qa2, qb2;
    float pr0[8], pr1[8], pr2[8];

    DN_LOAD(qa0, qb0, pr0, 0)
    DN_LOAD(qa1, qb1, pr1, 64)
    DN_LOAD(qa2, qb2, pr2, 128)
    DN_CW(qa0, qb0, pr0, As0, Bs0)
    BAR()

    DN_PH(0,0,1,1,0) DN_PH(1,1,2,0,1) DN_PH(2,2,0,1,0) DN_PH(3,0,1,0,1)
    DN_PH(4,1,2,1,0) DN_PH(5,2,0,0,1) DN_PH(6,0,1,1,0) DN_PH(7,0,0,0,1)

#pragma unroll
    for (int fi = 0; fi < 2; ++fi)
#pragma unroll
        for (int rr = 0; rr < 4; ++rr) {
            const int m = wm + (fi << 4) + (lg << 2) + rr;
            const int row = r0 + m;
            if (row < cnt) {
                int t; float wt;
                if (e < NE) { t = token_list[e * TT + row]; wt = weight_list[e * TT + row]; }
                else        { t = row; wt = 1.f; }
                atomicAdd(&out[(size_t)t * HH + n0 + wn + lm], wt * acc[fi][rr]);
            }
        }
}

extern "C" void kernel_launch(void* const* d_in, const int* in_sizes, int n_in,
                              void* d_out, int out_size, void* d_ws, size_t ws_size,
                              hipStream_t stream)
{
    const float* x       = (const float*)d_in[0];
    const float* gate_w  = (const float*)d_in[1];
    const float* w_gate  = (const float*)d_in[2];
    const float* w_up    = (const float*)d_in[3];
    const float* w_down  = (const float*)d_in[4];
    const float* ws_gate = (const float*)d_in[5];
    const float* ws_up   = (const float*)d_in[6];
    const float* ws_down = (const float*)d_in[7];
    float* out = (float*)d_out;

    // workspace: counts[16] | offs[17] | pad to 64 ints | token_list[16*1024] |
    // weight_list[16*1024] | rinter f16 [3072][512]
    int* counts = (int*)d_ws;
    int* offs = counts + 16;
    int* token_list = counts + 64;
    float* weight_list = (float*)(counts + 64 + NE * TT);
    f16* rinter = (f16*)(counts + 64 + 2 * NE * TT);

    hipMemsetAsync(counts, 0, 64, stream);
    hipMemsetAsync(out, 0, (size_t)TT * HH * sizeof(float), stream);
    router_k<<<dim3(TT / 4), 256, 0, stream>>>(x, gate_w, counts, token_list, weight_list);
    prefix_k<<<1, 64, 0, stream>>>(counts, offs);
    // grid: x = n-tile (always active -> spreads over all 8 XCDs), y = row-tile, z = expert
    gu_k<<<dim3(MM / 32, TT / 64, NE + 1), 256, 0, stream>>>(
        x, w_gate, w_up, ws_gate, ws_up, counts, offs, token_list, rinter);
    down_k<<<dim3(HH / 32, TT / 64, NE + 1), 256, 0, stream>>>(
        rinter, w_down, ws_down, counts, offs, token_list, weight_list, out);
}

// Round 10
// 115.176 us; speedup vs baseline: 1.0871x; 1.0871x over previous
//
#include <hip/hip_runtime.h>
#include <math.h>

#define TT 1024   // tokens
#define HH 1024   // hidden
#define MM 512    // moe intermediate
#define NE 16     // routed experts (blockIdx.z == NE -> shared expert)
// TOP_K = 2, SCALE = 2.5, NORM_TOPK = true

typedef _Float16 f16;
typedef _Float16 f16x8 __attribute__((ext_vector_type(8)));
typedef float f32x4 __attribute__((ext_vector_type(4)));

// async global->LDS, 16B per lane, LDS dest = uniform base + lane*16 (linear).
#define GLL(g, l) __builtin_amdgcn_global_load_lds(                         \
    (const __attribute__((address_space(1))) void*)(g),                     \
    (__attribute__((address_space(3))) void*)(l), 16, 0, 0)

#define SB() __builtin_amdgcn_sched_barrier(0)
#define WAITVM(N) { SB(); asm volatile("s_waitcnt vmcnt(" #N ")"); SB(); }
#define BARRIER() __builtin_amdgcn_s_barrier()

// ---------------- router ----------------
__global__ __launch_bounds__(256) void router_k(
    const float* __restrict__ x, const float* __restrict__ gate_w,
    int* __restrict__ counts, int* __restrict__ token_list, float* __restrict__ weight_list)
{
    const int wave = threadIdx.x >> 6;
    const int lane = threadIdx.x & 63;
    const int t = (blockIdx.x << 2) + wave;
    const float* xr = x + (size_t)t * HH;
    float xv[16];
#pragma unroll
    for (int i = 0; i < 16; ++i) xv[i] = xr[lane + (i << 6)];
    float sc[NE];
#pragma unroll
    for (int e = 0; e < NE; ++e) {
        const float* gr = gate_w + e * HH;
        float acc = 0.f;
#pragma unroll
        for (int i = 0; i < 16; ++i) acc = fmaf(xv[i], gr[lane + (i << 6)], acc);
#pragma unroll
        for (int off = 32; off > 0; off >>= 1) acc += __shfl_down(acc, off, 64);
        sc[e] = acc;   // valid on lane 0
    }
    if (lane == 0) {
        float l1 = -1e30f, l2 = -1e30f; int i1 = 0, i2 = 0;
#pragma unroll
        for (int e = 0; e < NE; ++e) {
            float v = sc[e];
            if (v > l1) { l2 = l1; i2 = i1; l1 = v; i1 = e; }
            else if (v > l2) { l2 = v; i2 = e; }
        }
        float w1 = 1.f / (1.f + __expf(-l1));
        float w2 = 1.f / (1.f + __expf(-l2));
        const float inv = 2.5f / (w1 + w2 + 1e-20f);
        w1 *= inv; w2 *= inv;
        int s1 = atomicAdd(&counts[i1], 1);
        token_list[i1 * TT + s1] = t;
        weight_list[i1 * TT + s1] = w1;
        int s2 = atomicAdd(&counts[i2], 1);
        token_list[i2 * TT + s2] = t;
        weight_list[i2 * TT + s2] = w2;
    }
}

__global__ void prefix_k(const int* __restrict__ counts, int* __restrict__ offs)
{
    if (threadIdx.x == 0 && blockIdx.x == 0) {
        int acc = 0;
#pragma unroll
        for (int e = 0; e < NE; ++e) { offs[e] = acc; acc += counts[e]; }
        offs[NE] = acc;
    }
}

// ================= fused gate/up =================
// BM=64, BN=32, BK=64, fp32 tiles in LDS via global_load_lds, dbuf.
// LDS layouts (linear, swizzle realized by pre-swizzled global source):
//   A[m][c]  holds x[tok m][k: c^(4*(m&7)) at 16B granularity]  -> frag b128 conflict-free
//   B[k][c]  holds w[k][n: c^(16*((k>>3)&1))]                   -> frag b32 2-way (free)
// Per wave per tile: 4 A + 2 Bg + 2 Bu = 8 global_load_lds (1KB each) -> vmcnt(8) counted.

#define GU_ISSUE(K0, AS, BG, BU) {                                          \
    _Pragma("unroll") for (int i = 0; i < 4; ++i)                           \
        GLL(pA[i] + (K0), &AS[aw + 4*i][0]);                                \
    _Pragma("unroll") for (int i = 0; i < 2; ++i) {                         \
        GLL(pBg[i] + (size_t)(K0) * MM, &BG[(w << 4) + 8*i][0]);            \
        GLL(pBu[i] + (size_t)(K0) * MM, &BU[(w << 4) + 8*i][0]); } }

#define GU_COMP(AS, BG, BU) {                                               \
    _Pragma("unroll") for (int h = 0; h < 2; ++h) {                         \
        const int kb = (h << 5) + (lg << 3);                                \
        const int xr = (lm & 7) << 2;                                       \
        f16x8 af[2];                                                        \
        _Pragma("unroll") for (int f = 0; f < 2; ++f) {                     \
            const int m = wm + (f << 4) + lm;                               \
            float4 lo = *(const float4*)&AS[m][kb ^ xr];                    \
            float4 hi = *(const float4*)&AS[m][(kb + 4) ^ xr];              \
            af[f] = (f16x8){(f16)lo.x,(f16)lo.y,(f16)lo.z,(f16)lo.w,        \
                            (f16)hi.x,(f16)hi.y,(f16)hi.z,(f16)hi.w};       \
        }                                                                   \
        const int bc = (wn + lm) ^ ((lg & 1) << 4);                         \
        f16x8 bg, bu;                                                       \
        _Pragma("unroll") for (int j = 0; j < 8; ++j) {                     \
            bg[j] = (f16)BG[kb + j][bc]; bu[j] = (f16)BU[kb + j][bc]; }     \
        _Pragma("unroll") for (int f = 0; f < 2; ++f) {                     \
            accg[f] = __builtin_amdgcn_mfma_f32_16x16x32_f16(af[f], bg, accg[f], 0, 0, 0); \
            accu[f] = __builtin_amdgcn_mfma_f32_16x16x32_f16(af[f], bu, accu[f], 0, 0, 0); } } }

__global__ __launch_bounds__(256) void gu_k(
    const float* __restrict__ x,
    const float* __restrict__ w_gate, const float* __restrict__ w_up,
    const float* __restrict__ ws_gate, const float* __restrict__ ws_up,
    const int* __restrict__ counts, const int* __restrict__ offs,
    const int* __restrict__ token_list, f16* __restrict__ rinter)
{
    const int e = blockIdx.z;
    int cnt, slot0;
    const float *wgp, *wup;
    if (e < NE) {
        cnt = counts[e]; slot0 = offs[e];
        wgp = w_gate + (size_t)e * HH * MM;
        wup = w_up   + (size_t)e * HH * MM;
    } else {
        cnt = TT; slot0 = 2 * TT;
        wgp = ws_gate; wup = ws_up;
    }
    const int r0 = blockIdx.y << 6;
    if (r0 >= cnt) return;
    const int n0 = blockIdx.x << 5;

    __shared__ float As0[64][64], As1[64][64];
    __shared__ float Bg0[64][32], Bg1[64][32];
    __shared__ float Bu0[64][32], Bu1[64][32];
    __shared__ int toks[64];

    const int tid = threadIdx.x;
    if (tid < 64) {
        int i = r0 + tid; if (i >= cnt) i = cnt - 1;
        toks[tid] = (e < NE) ? token_list[e * TT + i] : i;
    }
    __syncthreads();

    const int w = tid >> 6, lane = tid & 63;
    const int lm = lane & 15, lg = lane >> 4;
    const int wm = (w >> 1) << 5, wn = (w & 1) << 4;
    const int aw = w << 4;                      // A staging row base (16 rows/wave)

    // per-lane global pointers (swizzle folded in; phase adds K0)
    const float* pA[4];
#pragma unroll
    for (int i = 0; i < 4; ++i) {
        int m = aw + 4*i + (lane >> 4);
        pA[i] = x + (size_t)toks[m] * HH + 4 * ((lane & 15) ^ (m & 7));
    }
    const float* pBg[2]; const float* pBu[2];
#pragma unroll
    for (int i = 0; i < 2; ++i) {
        int kr = (w << 4) + 8*i + (lane >> 3);
        int sg = 4 * ((lane & 7) ^ ((i & 1) << 2));
        pBg[i] = wgp + (size_t)kr * MM + n0 + sg;
        pBu[i] = wup + (size_t)kr * MM + n0 + sg;
    }

    f32x4 accg[2] = {}, accu[2] = {};

    GU_ISSUE(0, As0, Bg0, Bu0)
#pragma unroll 1
    for (int t = 0; t < 14; t += 2) {
        GU_ISSUE((t + 1) << 6, As1, Bg1, Bu1)
        WAITVM(8) BARRIER();
        GU_COMP(As0, Bg0, Bu0)
        BARRIER();
        GU_ISSUE((t + 2) << 6, As0, Bg0, Bu0)
        WAITVM(8) BARRIER();
        GU_COMP(As1, Bg1, Bu1)
        BARRIER();
    }
    GU_ISSUE(15 << 6, As1, Bg1, Bu1)
    WAITVM(8) BARRIER();
    GU_COMP(As0, Bg0, Bu0)          // tile 14
    BARRIER();
    WAITVM(0) BARRIER();
    GU_COMP(As1, Bg1, Bu1)          // tile 15

    // epilogue: silu(g)*u -> f16; C/D: col=lane&15, row=(lane>>4)*4+reg
#pragma unroll
    for (int fi = 0; fi < 2; ++fi)
#pragma unroll
        for (int rr = 0; rr < 4; ++rr) {
            const int m = wm + (fi << 4) + (lg << 2) + rr;
            if (r0 + m < cnt) {
                float g = accg[fi][rr], u = accu[fi][rr];
                float s = g / (1.f + __expf(-g));
                rinter[(size_t)(slot0 + r0 + m) * MM + n0 + wn + lm] = (f16)(s * u);
            }
        }
}

// ================= down: out[token] += weight * (rinter @ Wd) =================
// A = rinter (f16) [64][64] linear-swizzled; B = Wd fp32 [64][32] as in gu.
// Per wave per tile: 2 A + 2 B = 4 loads -> vmcnt(4).

#define DN_ISSUE(K0, AS, BS) {                                              \
    _Pragma("unroll") for (int i = 0; i < 2; ++i) {                         \
        GLL(pa[i] + (K0), &AS[(w << 4) + 8*i][0]);                          \
        GLL(pb[i] + (size_t)(K0) * HH, &BS[(w << 4) + 8*i][0]); } }

#define DN_COMP(AS, BS) {                                                   \
    _Pragma("unroll") for (int h = 0; h < 2; ++h) {                         \
        const int kb = (h << 5) + (lg << 3);                                \
        const int xr = (lm & 7) << 3;                                       \
        f16x8 af[2];                                                        \
        _Pragma("unroll") for (int f = 0; f < 2; ++f)                       \
            af[f] = *(const f16x8*)&AS[wm + (f << 4) + lm][kb ^ xr];        \
        const int bc = (wn + lm) ^ ((lg & 1) << 4);                         \
        f16x8 bv;                                                           \
        _Pragma("unroll") for (int j = 0; j < 8; ++j) bv[j] = (f16)BS[kb + j][bc]; \
        _Pragma("unroll") for (int f = 0; f < 2; ++f)                       \
            acc[f] = __builtin_amdgcn_mfma_f32_16x16x32_f16(af[f], bv, acc[f], 0, 0, 0); } }

__global__ __launch_bounds__(256) void down_k(
    const f16* __restrict__ rinter,
    const float* __restrict__ w_down, const float* __restrict__ ws_down,
    const int* __restrict__ counts, const int* __restrict__ offs,
    const int* __restrict__ token_list, const float* __restrict__ weight_list,
    float* __restrict__ out)
{
    const int e = blockIdx.z;
    int cnt, slot0; const float* wdp;
    if (e < NE) { cnt = counts[e]; slot0 = offs[e]; wdp = w_down + (size_t)e * MM * HH; }
    else        { cnt = TT; slot0 = 2 * TT; wdp = ws_down; }
    const int r0 = blockIdx.y << 6;
    if (r0 >= cnt) return;
    const int n0 = blockIdx.x << 5;   // of HH

    __shared__ f16  As0[64][64], As1[64][64];
    __shared__ float Bs0[64][32], Bs1[64][32];

    const int tid = threadIdx.x;
    const int w = tid >> 6, lane = tid & 63;
    const int lm = lane & 15, lg = lane >> 4;
    const int wm = (w >> 1) << 5, wn = (w & 1) << 4;

    const f16* pa[2]; const float* pb[2];
#pragma unroll
    for (int i = 0; i < 2; ++i) {
        int m = (w << 4) + 8*i + (lane >> 3);       // A row (slots are contiguous)
        pa[i] = rinter + (size_t)(slot0 + r0 + m) * MM + 8 * ((lane & 7) ^ (m & 7));
        int kr = (w << 4) + 8*i + (lane >> 3);      // B k-row
        pb[i] = wdp + (size_t)kr * HH + n0 + 4 * ((lane & 7) ^ ((i & 1) << 2));
    }

    f32x4 acc[2] = {};

    DN_ISSUE(0, As0, Bs0)
#pragma unroll 1
    for (int t = 0; t < 6; t += 2) {
        DN_ISSUE((t + 1) << 6, As1, Bs1)
        WAITVM(4) BARRIER();
        DN_COMP(As0, Bs0)
        BARRIER();
        DN_ISSUE((t + 2) << 6, As0, Bs0)
        WAITVM(4) BARRIER();
        DN_COMP(As1, Bs1)
        BARRIER();
    }
    DN_ISSUE(7 << 6, As1, Bs1)
    WAITVM(4) BARRIER();
    DN_COMP(As0, Bs0)               // tile 6
    BARRIER();
    WAITVM(0) BARRIER();
    DN_COMP(As1, Bs1)               // tile 7

#pragma unroll
    for (int fi = 0; fi < 2; ++fi)
#pragma unroll
        for (int rr = 0; rr < 4; ++rr) {
            const int m = wm + (fi << 4) + (lg << 2) + rr;
            const int row = r0 + m;
            if (row < cnt) {
                int t; float wt;
                if (e < NE) { t = token_list[e * TT + row]; wt = weight_list[e * TT + row]; }
                else        { t = row; wt = 1.f; }
                atomicAdd(&out[(size_t)t * HH + n0 + wn + lm], wt * acc[fi][rr]);
            }
        }
}

extern "C" void kernel_launch(void* const* d_in, const int* in_sizes, int n_in,
                              void* d_out, int out_size, void* d_ws, size_t ws_size,
                              hipStream_t stream)
{
    const float* x       = (const float*)d_in[0];
    const float* gate_w  = (const float*)d_in[1];
    const float* w_gate  = (const float*)d_in[2];
    const float* w_up    = (const float*)d_in[3];
    const float* w_down  = (const float*)d_in[4];
    const float* ws_gate = (const float*)d_in[5];
    const float* ws_up   = (const float*)d_in[6];
    const float* ws_down = (const float*)d_in[7];
    float* out = (float*)d_out;

    // workspace: counts[16] | offs[17] | pad to 64 ints | token_list[16*1024] |
    // weight_list[16*1024] | rinter f16 [3072][512]
    int* counts = (int*)d_ws;
    int* offs = counts + 16;
    int* token_list = counts + 64;
    float* weight_list = (float*)(counts + 64 + NE * TT);
    f16* rinter = (f16*)(counts + 64 + 2 * NE * TT);

    hipMemsetAsync(counts, 0, 64, stream);
    hipMemsetAsync(out, 0, (size_t)TT * HH * sizeof(float), stream);
    router_k<<<dim3(TT / 4), 256, 0, stream>>>(x, gate_w, counts, token_list, weight_list);
    prefix_k<<<1, 64, 0, stream>>>(counts, offs);
    // grid: x = n-tile (always active -> spreads over all 8 XCDs), y = row-tile, z = expert
    gu_k<<<dim3(MM / 32, TT / 64, NE + 1), 256, 0, stream>>>(
        x, w_gate, w_up, ws_gate, ws_up, counts, offs, token_list, rinter);
    down_k<<<dim3(HH / 32, TT / 64, NE + 1), 256, 0, stream>>>(
        rinter, w_down, ws_down, counts, offs, token_list, weight_list, out);
}